// Round 8
// baseline (1372.308 us; speedup 1.0000x reference)
//
#include <hip/hip_runtime.h>
#include <hip/hip_cooperative_groups.h>
#include <cstddef>
#include <cstdint>

namespace cg = cooperative_groups;

#define NB 8
#define SEQ 4096
#define HIDDIM 4096
#define NHEAD 32
#define HDIM 128
#define FFNDIM 16384
#define ATTN_SCALE 0.08838834764831845f
#define NBLK 256
#define NTHR 512

__device__ __forceinline__ float wave_sum64(float v) {
#pragma unroll
  for (int off = 32; off > 0; off >>= 1) v += __shfl_xor(v, off, 64);
  return v;
}

// positions may arrive as int32 (harness default) or int64 (reference dtype).
__device__ __forceinline__ int get_pos(const int* __restrict__ p, int b) {
  const bool is64 = ((p[1] | p[3] | p[5] | p[7]) == 0);
  return is64 ? p[2 * b] : p[b];
}

// single-pass LN stats for all 8 rows; wave w reduces row w. mu/rsd in LDS.
__device__ __forceinline__ void ln_stats(const float* __restrict__ in,
                                         float* mu, float* rsd, int t) {
  const int wv = t >> 6, lane = t & 63;
  float s = 0.f, s2 = 0.f;
  for (int i = lane; i < HIDDIM; i += 64) {
    const float v = in[(size_t)wv * HIDDIM + i];
    s += v;
    s2 += v * v;
  }
  s = wave_sum64(s);
  s2 = wave_sum64(s2);
  if (lane == 0) {
    const float m = s * (1.0f / HIDDIM);
    mu[wv] = m;
    rsd[wv] = rsqrtf(s2 * (1.0f / HIDDIM) - m * m + 1e-5f);
  }
}

// GEMM item: 1024 cols (float2/thread), nrows K-rows, x staged in xs[row][8].
// Writes per-b partial rows at partOut + b*N + col.
__device__ __forceinline__ void gemm_item(const float* __restrict__ W, int N,
                                          size_t i0, int nrows, int jbase,
                                          const float* xs,
                                          float* __restrict__ partOut, int t) {
  const int j = jbase + t * 2;
  const float* __restrict__ wp = W + i0 * N + j;
  float2 acc[8];
#pragma unroll
  for (int b = 0; b < 8; ++b) acc[b] = {0.f, 0.f};
#pragma unroll 8
  for (int i = 0; i < nrows; ++i) {
    const float2 w = *reinterpret_cast<const float2*>(wp + (size_t)i * N);
    const float* xr = xs + i * 8;
#pragma unroll
    for (int b = 0; b < 8; ++b) {
      acc[b].x = fmaf(xr[b], w.x, acc[b].x);
      acc[b].y = fmaf(xr[b], w.y, acc[b].y);
    }
  }
#pragma unroll
  for (int b = 0; b < 8; ++b)
    *reinterpret_cast<float2*>(partOut + (size_t)b * N + j) = acc[b];
}

__global__ __launch_bounds__(NTHR, 2) void mega(
    const float* __restrict__ hs, const float* __restrict__ kcache,
    const float* __restrict__ vcache, const float* __restrict__ wqkv,
    const float* __restrict__ wdense, const float* __restrict__ wfc1,
    const float* __restrict__ wfc2, const float* __restrict__ ln1w,
    const float* __restrict__ ln1b, const float* __restrict__ ln2w,
    const float* __restrict__ ln2b, const int* __restrict__ posp,
    float* __restrict__ out, float* __restrict__ ws) {
  cg::grid_group gg = cg::this_grid();
  const int blk = blockIdx.x, t = threadIdx.x;

  float* qws = ws;                  // 32768
  float* kws = qws + 32768;         // 32768
  float* vws = kws + 32768;         // 32768
  float* attnt = vws + 32768;       // 32768, layout (i=h*128+d, b)
  float* hidden2 = attnt + 32768;   // 32768, layout (b, i)
  float* gt = hidden2 + 32768;      // 131072, layout (j, b)
  float* Mp = gt + 131072;          // 4096
  float* Lp = Mp + 4096;            // 4096
  float* Ap = Lp + 4096;            // 524288
  float* part = Ap + 524288 + 64;   // <= 6.3M floats

  __shared__ float xs[512 * 8];     // 16 KB x-staging
  __shared__ float mu[8], rsd[8];
  __shared__ float qp[4][HDIM], kp[4][HDIM], vp[4][HDIM];  // 6 KB
  __shared__ float sa[16][HDIM];    // 8 KB
  __shared__ float sm[16], sl[16];

  // ---------- Phase A: LN1 (redundant per block) + qkv GEMM
  // items: 12 jtiles(1024 cols) x 64 kchunks(64) = 768 -> 3/block exact
  ln_stats(hs, mu, rsd, t);
  __syncthreads();
  for (int it = blk; it < 768; it += NBLK) {
    const int jt = it % 12;
    const int ck = it / 12;
    const size_t i0 = (size_t)ck * 64;
    {
      const int i = t >> 3, b = t & 7;
      const int ii = (int)i0 + i;
      const float v = hs[(size_t)b * HIDDIM + ii];
      xs[i * 8 + b] = (v - mu[b]) * rsd[b] * (ln1w[ii] + 1.f) + ln1b[ii];
    }
    __syncthreads();
    gemm_item(wqkv, 3 * HIDDIM, i0, 64, jt * 1024, xs,
              part + (size_t)ck * 8 * (3 * HIDDIM), t);
    __syncthreads();
  }
  __threadfence();
  gg.sync();

  // ---------- Phase B: reduce 64 qkv partials + RoPE -> qws/kws/vws
  {
    const int b = blk >> 5, h = blk & 31;
    const int d = t & 127, g = t >> 7;  // 4 chunk-groups of 16
    float q = 0.f, k = 0.f, v = 0.f;
    for (int c = g * 16; c < g * 16 + 16; ++c) {
      const float* p = part + (size_t)(c * 8 + b) * (3 * HIDDIM) + h * HDIM + d;
      q += p[0];
      k += p[HIDDIM];
      v += p[2 * HIDDIM];
    }
    qp[g][d] = q;
    kp[g][d] = k;
    vp[g][d] = v;
    __syncthreads();
    if (t < HDIM) {
      qp[0][t] = qp[0][t] + qp[1][t] + qp[2][t] + qp[3][t];
      kp[0][t] = kp[0][t] + kp[1][t] + kp[2][t] + kp[3][t];
      vp[0][t] = vp[0][t] + vp[1][t] + vp[2][t] + vp[3][t];
    }
    __syncthreads();
    if (t < HDIM) {
      const int pos = get_pos(posp, b);
      float qv = qp[0][t], kv = kp[0][t];
      if (t < 64) {
        const int f = t & 31;
        const float ang = (float)pos * powf(10000.0f, -(float)f * (1.0f / 32.0f));
        const float cs = cosf(ang), sn = sinf(ang);
        if (t < 32) {
          qv = qp[0][t] * cs - qp[0][t + 32] * sn;
          kv = kp[0][t] * cs - kp[0][t + 32] * sn;
        } else {
          qv = qp[0][t] * cs + qp[0][t - 32] * sn;
          kv = kp[0][t] * cs + kp[0][t - 32] * sn;
        }
      }
      const size_t o = (size_t)b * HIDDIM + h * HDIM + t;
      qws[o] = qv;
      kws[o] = kv;
      vws[o] = vp[0][t];
    }
  }
  __threadfence();
  gg.sync();

  // ---------- Phase C: attention, STATIC assignment (no atomics)
  // item: c = item>>8 (s-chunk of 256), pair = item&255 (b = pair&7, h = pair>>3)
  // block blk handles pair=blk for c = 0..15 (validity is block-uniform).
  for (int item = blk; item < 4096; item += NBLK) {
    const int c = item >> 8;
    const int pair = item & 255;
    const int b = pair & 7, h = pair >> 3;
    const int pos = get_pos(posp, b);
    const int s0 = c * 256;
    if (s0 > pos) continue;
    const int s1 = min(s0 + 256, pos + 1);
    const int hw = t >> 5, l32 = t & 31, d4 = l32 * 4;
    const float4 qv = *reinterpret_cast<const float4*>(
        qws + (size_t)b * HIDDIM + h * HDIM + d4);
    const float* kb = kcache + ((size_t)b * SEQ * NHEAD + h) * HDIM + d4;
    const float* vb = vcache + ((size_t)b * SEQ * NHEAD + h) * HDIM + d4;
    const float* knp = kws + (size_t)b * HIDDIM + h * HDIM + d4;
    const float* vnp = vws + (size_t)b * HIDDIM + h * HDIM + d4;
    float m = -1e30f, l = 0.f;
    float4 acc = {0.f, 0.f, 0.f, 0.f};
    const int rbase = s0 + hw * 16;
#pragma unroll 4
    for (int r = 0; r < 16; ++r) {
      const int s = rbase + r;
      const bool valid = (s < s1);
      const int sc = valid ? s : s0;
      const float* kp_ = (sc == pos) ? knp : kb + (size_t)sc * (NHEAD * HDIM);
      const float* vp_ = (sc == pos) ? vnp : vb + (size_t)sc * (NHEAD * HDIM);
      const float4 kk = *reinterpret_cast<const float4*>(kp_);
      const float4 vv = *reinterpret_cast<const float4*>(vp_);
      float p = qv.x * kk.x + qv.y * kk.y + qv.z * kk.z + qv.w * kk.w;
#pragma unroll
      for (int off = 16; off > 0; off >>= 1) p += __shfl_xor(p, off, 64);
      p = valid ? p * ATTN_SCALE : -2e30f;
      const float mn = fmaxf(m, p);
      const float cf = __expf(m - mn);
      const float pw = __expf(p - mn);
      l = l * cf + pw;
      acc.x = acc.x * cf + pw * vv.x;
      acc.y = acc.y * cf + pw * vv.y;
      acc.z = acc.z * cf + pw * vv.z;
      acc.w = acc.w * cf + pw * vv.w;
      m = mn;
    }
    *reinterpret_cast<float4*>(&sa[hw][d4]) = acc;
    if (l32 == 0) {
      sm[hw] = m;
      sl[hw] = l;
    }
    __syncthreads();
    if (t < HDIM) {
      float M = -1e30f;
#pragma unroll
      for (int w2 = 0; w2 < 16; ++w2) M = fmaxf(M, sm[w2]);
      float L = 0.f, A = 0.f;
#pragma unroll
      for (int w2 = 0; w2 < 16; ++w2) {
        const float e = __expf(sm[w2] - M);
        L += e * sl[w2];
        A += e * sa[w2][t];
      }
      const size_t idx = (size_t)pair * 16 + c;
      if (t == 0) {
        Mp[idx] = M;
        Lp[idx] = L;
      }
      Ap[idx * HDIM + t] = A;
    }
    __syncthreads();
  }
  __threadfence();
  gg.sync();

  // ---------- Phase D: combine chunks -> attnt (i,b)
  if (t < HDIM) {
    const int b = blk & 7, h = blk >> 3;
    const int pos = get_pos(posp, b);
    const int nc = pos / 256 + 1;
    const size_t base = (size_t)blk * 16;
    float M = -1e30f;
    for (int c = 0; c < nc; ++c) M = fmaxf(M, Mp[base + c]);
    float L = 0.f, A = 0.f;
    for (int c = 0; c < nc; ++c) {
      const float e = __expf(Mp[base + c] - M);
      L += e * Lp[base + c];
      A += e * Ap[(base + c) * HDIM + t];
    }
    attnt[(size_t)(h * HDIM + t) * NB + b] = A / L;
  }
  __threadfence();
  gg.sync();

  // ---------- Phase E: dense GEMM (items: 4 jt x 64 ck = 256, 1/block)
  {
    const int jt = blk & 3;
    const int ck = blk >> 2;
    const size_t i0 = (size_t)ck * 64;
    xs[t] = attnt[i0 * 8 + t];  // 64 rows x 8 b, contiguous
    __syncthreads();
    gemm_item(wdense, HIDDIM, i0, 64, jt * 1024, xs,
              part + (size_t)ck * 8 * HIDDIM, t);
  }
  __threadfence();
  gg.sync();

  // ---------- Phase F: hidden2 = hs + sum of 64 dense partials
  {
    const int idx = blk * NTHR + t;
    const int g = idx >> 2, sub = idx & 3;
    if (g < 8192) {
      const float4* p4 = reinterpret_cast<const float4*>(part);
      float4 v = {0.f, 0.f, 0.f, 0.f};
      for (int c = sub * 16; c < sub * 16 + 16; ++c) {
        const float4 p = p4[(size_t)c * 8192 + g];
        v.x += p.x; v.y += p.y; v.z += p.z; v.w += p.w;
      }
#pragma unroll
      for (int off = 1; off < 4; off <<= 1) {
        v.x += __shfl_xor(v.x, off, 64);
        v.y += __shfl_xor(v.y, off, 64);
        v.z += __shfl_xor(v.z, off, 64);
        v.w += __shfl_xor(v.w, off, 64);
      }
      if (sub == 0) {
        const float4 hv = reinterpret_cast<const float4*>(hs)[g];
        float4 o = {v.x + hv.x, v.y + hv.y, v.z + hv.z, v.w + hv.w};
        reinterpret_cast<float4*>(hidden2)[g] = o;
      }
    }
  }
  __threadfence();
  gg.sync();

  // ---------- Phase G: LN2 (redundant) + fc1 GEMM
  // items: 32 jt x 8 ck(512) = 256, 1/block
  ln_stats(hidden2, mu, rsd, t);
  __syncthreads();
  {
    const int jt = blk & 31;
    const int ck = blk >> 5;
    const size_t i0 = (size_t)ck * 512;
#pragma unroll
    for (int r = 0; r < 8; ++r) {
      const int idx2 = r * NTHR + t;
      const int i = idx2 >> 3, b = idx2 & 7;
      const int ii = (int)i0 + i;
      const float v = hidden2[(size_t)b * HIDDIM + ii];
      xs[idx2] = (v - mu[b]) * rsd[b] * (ln2w[ii] + 1.f) + ln2b[ii];
    }
    __syncthreads();
    gemm_item(wfc1, 2 * FFNDIM, i0, 512, jt * 1024, xs,
              part + (size_t)ck * 8 * (2 * FFNDIM), t);
  }
  __threadfence();
  gg.sync();

  // ---------- Phase H: gate+silu -> gt (j,b)
  {
    const int idx = blk * NTHR + t;
    if (idx < 32768) {
      const int j4 = idx >> 3, b = idx & 7;
      const int j = j4 * 4;
      float4 h1 = {0.f, 0.f, 0.f, 0.f}, h2 = {0.f, 0.f, 0.f, 0.f};
      for (int c = 0; c < 8; ++c) {
        const float* p = part + (size_t)(c * 8 + b) * (2 * FFNDIM);
        const float4 a = *reinterpret_cast<const float4*>(p + j);
        const float4 g2 = *reinterpret_cast<const float4*>(p + FFNDIM + j);
        h1.x += a.x; h1.y += a.y; h1.z += a.z; h1.w += a.w;
        h2.x += g2.x; h2.y += g2.y; h2.z += g2.z; h2.w += g2.w;
      }
      const float* h1v = &h1.x;
      const float* h2v = &h2.x;
#pragma unroll
      for (int jj = 0; jj < 4; ++jj) {
        const float gv = (h1v[jj] / (1.f + __expf(-h1v[jj]))) * h2v[jj];
        gt[(size_t)(j + jj) * NB + b] = gv;
      }
    }
  }
  __threadfence();
  gg.sync();

  // ---------- Phase I: fc2 GEMM (items: 4 jt x 64 ck(256) = 256, 1/block)
  {
    const int jt = blk & 3;
    const int ck = blk >> 2;
    const size_t i0 = (size_t)ck * 256;
#pragma unroll
    for (int r = 0; r < 4; ++r) {
      const int idx2 = r * NTHR + t;
      xs[idx2] = gt[i0 * 8 + idx2];  // (j,b) contiguous
    }
    __syncthreads();
    gemm_item(wfc2, HIDDIM, i0, 256, jt * 1024, xs,
              part + (size_t)ck * 8 * HIDDIM, t);
  }
  __threadfence();
  gg.sync();

  // ---------- Phase J: out = hidden2 + sum of 64 fc2 partials
  {
    const int idx = blk * NTHR + t;
    const int g = idx >> 2, sub = idx & 3;
    if (g < 8192) {
      const float4* p4 = reinterpret_cast<const float4*>(part);
      float4 v = {0.f, 0.f, 0.f, 0.f};
      for (int c = sub * 16; c < sub * 16 + 16; ++c) {
        const float4 p = p4[(size_t)c * 8192 + g];
        v.x += p.x; v.y += p.y; v.z += p.z; v.w += p.w;
      }
#pragma unroll
      for (int off = 1; off < 4; off <<= 1) {
        v.x += __shfl_xor(v.x, off, 64);
        v.y += __shfl_xor(v.y, off, 64);
        v.z += __shfl_xor(v.z, off, 64);
        v.w += __shfl_xor(v.w, off, 64);
      }
      if (sub == 0) {
        const float4 hv = reinterpret_cast<const float4*>(hidden2)[g];
        float4 o = {v.x + hv.x, v.y + hv.y, v.z + hv.z, v.w + hv.w};
        reinterpret_cast<float4*>(out)[g] = o;
      }
    }
  }
}

extern "C" void kernel_launch(void* const* d_in, const int* in_sizes, int n_in,
                              void* d_out, int out_size, void* d_ws, size_t ws_size,
                              hipStream_t stream) {
  const float* hs = (const float*)d_in[0];
  const float* kc = (const float*)d_in[1];
  const float* vc = (const float*)d_in[2];
  const float* wqkv = (const float*)d_in[3];
  const float* wdense = (const float*)d_in[4];
  const float* wfc1 = (const float*)d_in[5];
  const float* wfc2 = (const float*)d_in[6];
  const float* ln1w = (const float*)d_in[7];
  const float* ln1b = (const float*)d_in[8];
  const float* ln2w = (const float*)d_in[9];
  const float* ln2b = (const float*)d_in[10];
  const int* posp = (const int*)d_in[11];
  float* outp = (float*)d_out;
  float* wsp = (float*)d_ws;

  void* args[] = {&hs,   &kc,   &vc,   &wqkv, &wdense, &wfc1, &wfc2,
                  &ln1w, &ln1b, &ln2w, &ln2b, &posp,   &outp, &wsp};
  hipLaunchCooperativeKernel((void*)mega, dim3(NBLK), dim3(NTHR), args, 0,
                             stream);
}

// Round 9
// 416.622 us; speedup vs baseline: 3.2939x; 3.2939x over previous
//
#include <hip/hip_runtime.h>
#include <cstddef>
#include <cstdint>

#define NB 8
#define SEQ 4096
#define HIDDIM 4096
#define NHEAD 32
#define HDIM 128
#define FFNDIM 16384
#define ATTN_SCALE 0.08838834764831845f

// positions may arrive as int32 (harness default) or int64 (reference dtype).
__device__ __forceinline__ int get_pos(const int* __restrict__ p, int b) {
  const bool is64 = ((p[1] | p[3] | p[5] | p[7]) == 0);
  return is64 ? p[2 * b] : p[b];
}

// LN stats for 8 rows with 256 threads: 32-lane group r handles row r.
__device__ __forceinline__ void ln_stats256(const float* __restrict__ in,
                                            int t, float* mu, float* rsd) {
  const int r = t >> 5, l = t & 31;
  const float4* row = reinterpret_cast<const float4*>(in + (size_t)r * HIDDIM);
  float s = 0.f, s2 = 0.f;
  for (int it = l; it < HIDDIM / 4; it += 32) {
    const float4 v = row[it];
    s += v.x + v.y + v.z + v.w;
    s2 += v.x * v.x + v.y * v.y + v.z * v.z + v.w * v.w;
  }
#pragma unroll
  for (int off = 16; off > 0; off >>= 1) {
    s += __shfl_xor(s, off, 32);
    s2 += __shfl_xor(s2, off, 32);
  }
  if (l == 0) {
    const float m = s * (1.0f / HIDDIM);
    mu[r] = m;
    rsd[r] = rsqrtf(s2 * (1.0f / HIDDIM) - m * m + 1e-5f);
  }
}

// Skinny GEMM core, M=8: thread owns 4 cols; x-tile in LDS (R2-proven).
// Writes 8 partial rows at partOut + b*N + col.
__device__ __forceinline__ void gemm_core(const float* __restrict__ W, int N,
                                          size_t i0, int nrows, int jbase,
                                          const float* xs,
                                          float* __restrict__ partOut, int t) {
  const int j0 = jbase + t * 4;
  const float* __restrict__ wp = W + i0 * N + j0;
  float4 a0 = {0, 0, 0, 0}, a1 = {0, 0, 0, 0}, a2 = {0, 0, 0, 0}, a3 = {0, 0, 0, 0};
  float4 a4 = {0, 0, 0, 0}, a5 = {0, 0, 0, 0}, a6 = {0, 0, 0, 0}, a7 = {0, 0, 0, 0};
#pragma unroll 4
  for (int i = 0; i < nrows; ++i) {
    const float4 w = *reinterpret_cast<const float4*>(wp + (size_t)i * N);
    const float4 xa = *reinterpret_cast<const float4*>(xs + i * 8);
    const float4 xb = *reinterpret_cast<const float4*>(xs + i * 8 + 4);
#define ACC4(A, sxx)                                                          \
  A.x = fmaf(sxx, w.x, A.x);                                                  \
  A.y = fmaf(sxx, w.y, A.y);                                                  \
  A.z = fmaf(sxx, w.z, A.z);                                                  \
  A.w = fmaf(sxx, w.w, A.w);
    ACC4(a0, xa.x) ACC4(a1, xa.y) ACC4(a2, xa.z) ACC4(a3, xa.w)
    ACC4(a4, xb.x) ACC4(a5, xb.y) ACC4(a6, xb.z) ACC4(a7, xb.w)
#undef ACC4
  }
  float* op = partOut + j0;
  *reinterpret_cast<float4*>(op) = a0; op += N;
  *reinterpret_cast<float4*>(op) = a1; op += N;
  *reinterpret_cast<float4*>(op) = a2; op += N;
  *reinterpret_cast<float4*>(op) = a3; op += N;
  *reinterpret_cast<float4*>(op) = a4; op += N;
  *reinterpret_cast<float4*>(op) = a5; op += N;
  *reinterpret_cast<float4*>(op) = a6; op += N;
  *reinterpret_cast<float4*>(op) = a7;
}

// ---------- qkv with fused LN1: 768 blocks = 12 jt x 64 ck (3/CU)
__global__ __launch_bounds__(256) void qkv_ln(
    const float* __restrict__ hs, const float* __restrict__ w,
    const float* __restrict__ bias, const float* __restrict__ W,
    float* __restrict__ part) {
  __shared__ float mu[8], rsd[8];
  __shared__ float xs[64 * 8];
  const int t = threadIdx.x;
  const int jt = blockIdx.x % 12, ck = blockIdx.x / 12;
  const size_t i0 = (size_t)ck * 64;
  ln_stats256(hs, t, mu, rsd);
  __syncthreads();
#pragma unroll
  for (int r = 0; r < 2; ++r) {
    const int idx = r * 256 + t;
    const int i = idx >> 3, b = idx & 7;
    const int ii = (int)i0 + i;
    const float v = hs[(size_t)b * HIDDIM + ii];
    xs[idx] = (v - mu[b]) * rsd[b] * (w[ii] + 1.f) + bias[ii];
  }
  __syncthreads();
  gemm_core(W, 3 * HIDDIM, i0, 64, jt * 1024, xs,
            part + (size_t)ck * 8 * (3 * HIDDIM), t);
}

// ---------- reduce 64 qkv partials (float4) + RoPE (R6 body)
__global__ __launch_bounds__(128) void rope_reduce(const float* __restrict__ part, int nchunk,
                                                   const int* __restrict__ posp,
                                                   float* __restrict__ qo,
                                                   float* __restrict__ ko,
                                                   float* __restrict__ vo) {
  const int blk = blockIdx.x;
  const int b = blk >> 5, h = blk & 31;
  const int t = threadIdx.x;
  const int role = t >> 5;
  const int d4 = (t & 31) * 4;
  const int col = h * HDIM + d4;
  __shared__ float qsh[HDIM], ksh[HDIM];
  float4 acc = {0.f, 0.f, 0.f, 0.f};
  if (role < 3) {
    const size_t off = (size_t)role * HIDDIM + col;
    for (int c = 0; c < nchunk; ++c) {
      const float4 p = *reinterpret_cast<const float4*>(
          part + ((size_t)c * NB + b) * (3 * HIDDIM) + off);
      acc.x += p.x; acc.y += p.y; acc.z += p.z; acc.w += p.w;
    }
    if (role == 0) *reinterpret_cast<float4*>(&qsh[d4]) = acc;
    if (role == 1) *reinterpret_cast<float4*>(&ksh[d4]) = acc;
  }
  __syncthreads();
  if (role < 2) {
    const float* sh = role ? ksh : qsh;
    const float pos = (float)get_pos(posp, b);
    float4 o;
    float* ov = &o.x;
#pragma unroll
    for (int j = 0; j < 4; ++j) {
      const int d = d4 + j;
      if (d < 64) {
        const int f = d & 31;
        const float ang = pos * powf(10000.0f, -(float)f * (1.0f / 32.0f));
        const float cs = cosf(ang), sn = sinf(ang);
        ov[j] = (d < 32) ? sh[d] * cs - sh[d + 32] * sn
                         : sh[d] * cs + sh[d - 32] * sn;
      } else {
        ov[j] = sh[d];
      }
    }
    float* dst = (role ? ko : qo) + (size_t)b * HIDDIM + col;
    *reinterpret_cast<float4*>(dst) = o;
  } else if (role == 2) {
    *reinterpret_cast<float4*>(vo + (size_t)b * HIDDIM + col) = acc;
  }
}

// ---------- flash-decoding split (R6 body, passed)
__global__ __launch_bounds__(256) void attn_split(
    const float* __restrict__ kc, const float* __restrict__ vc,
    const float* __restrict__ q, const float* __restrict__ kn,
    const float* __restrict__ vn, const int* __restrict__ posp,
    float* __restrict__ Mp, float* __restrict__ Lp, float* __restrict__ Ap) {
  const int c = blockIdx.x, h = blockIdx.y, b = blockIdx.z;
  const int pos = get_pos(posp, b);
  const int s0 = c * 256;
  if (s0 > pos) return;
  const int s1 = min(s0 + 256, pos + 1);
  const int wid = threadIdx.x >> 6, lane = threadIdx.x & 63;
  const int half = lane >> 5;
  const int d4 = (lane & 31) * 4;
  const float4 qv = *reinterpret_cast<const float4*>(q + (size_t)b * HIDDIM + h * HDIM + d4);
  const float* kb = kc + ((size_t)b * SEQ * NHEAD + h) * HDIM + d4;
  const float* vb = vc + ((size_t)b * SEQ * NHEAD + h) * HDIM + d4;
  const float* knp = kn + (size_t)b * HIDDIM + h * HDIM + d4;
  const float* vnp = vn + (size_t)b * HIDDIM + h * HDIM + d4;
  float m = -1e30f, l = 0.f;
  float4 acc = {0.f, 0.f, 0.f, 0.f};
  for (int sb = s0; sb < s1; sb += 8) {
    const int s = sb + wid * 2 + half;
    const float* kp = (s == pos) ? knp : kb + (size_t)s * (NHEAD * HDIM);
    const float* vp = (s == pos) ? vnp : vb + (size_t)s * (NHEAD * HDIM);
    const float4 kk = *reinterpret_cast<const float4*>(kp);
    const float4 vv = *reinterpret_cast<const float4*>(vp);
    float p = qv.x * kk.x + qv.y * kk.y + qv.z * kk.z + qv.w * kk.w;
#pragma unroll
    for (int off = 16; off > 0; off >>= 1) p += __shfl_xor(p, off, 64);
    p = (s < s1) ? p * ATTN_SCALE : -2e30f;
    const float mn = fmaxf(m, p);
    const float cf = __expf(m - mn);
    const float pw = __expf(p - mn);
    l = l * cf + pw;
    acc.x = acc.x * cf + pw * vv.x;
    acc.y = acc.y * cf + pw * vv.y;
    acc.z = acc.z * cf + pw * vv.z;
    acc.w = acc.w * cf + pw * vv.w;
    m = mn;
  }
  __shared__ float sm[8], sl[8], sa[8][HDIM];
  const int st = wid * 2 + half;
  *reinterpret_cast<float4*>(&sa[st][d4]) = acc;
  if ((lane & 31) == 0) { sm[st] = m; sl[st] = l; }
  __syncthreads();
  if (threadIdx.x < HDIM) {
    const int d = threadIdx.x;
    float M = -1e30f;
#pragma unroll
    for (int w2 = 0; w2 < 8; ++w2) M = fmaxf(M, sm[w2]);
    float L = 0.f, A = 0.f;
#pragma unroll
    for (int w2 = 0; w2 < 8; ++w2) {
      const float e = __expf(sm[w2] - M);
      L += e * sl[w2];
      A += e * sa[w2][d];
    }
    const size_t idx = (size_t)(b * NHEAD + h) * 16 + c;
    if (d == 0) { Mp[idx] = M; Lp[idx] = L; }
    Ap[idx * HDIM + d] = A;
  }
}

// ---------- dense with fused chunk-combine: 512 blocks = 4 jt x 128 ck (2/CU)
__global__ __launch_bounds__(256) void dense_comb(
    const float* __restrict__ Mp, const float* __restrict__ Lp,
    const float* __restrict__ Ap, const int* __restrict__ posp,
    const float* __restrict__ W, float* __restrict__ part) {
  __shared__ float xs[32 * 8];
  const int t = threadIdx.x;
  const int jt = blockIdx.x & 3, ck = blockIdx.x >> 2;
  const size_t i0 = (size_t)ck * 32;
  {
    const int i = (int)i0 + (t >> 3), b = t & 7;
    const int h = i >> 7, d = i & 127;
    const int pos = get_pos(posp, b);
    const int nc = pos / 256 + 1;
    const size_t base = (size_t)(b * NHEAD + h) * 16;
    float M = -1e30f;
    for (int c = 0; c < nc; ++c) M = fmaxf(M, Mp[base + c]);
    float L = 0.f, A = 0.f;
    for (int c = 0; c < nc; ++c) {
      const float e = __expf(Mp[base + c] - M);
      L += e * Lp[base + c];
      A += e * Ap[(base + c) * HDIM + d];
    }
    xs[t] = A / L;  // t == (i-i0)*8 + b
  }
  __syncthreads();
  gemm_core(W, HIDDIM, i0, 32, jt * 1024, xs, part + (size_t)ck * 8 * HIDDIM, t);
}

// ---------- out = base + sum of 128 chunk partials (4 lanes per float4)
__global__ __launch_bounds__(256) void reduce_add4(const float* __restrict__ part,
                                                   const float* __restrict__ base,
                                                   float* __restrict__ out) {
  const int idx = blockIdx.x * 256 + threadIdx.x;
  const int g = idx >> 2, sub = idx & 3;
  const float4* p4 = reinterpret_cast<const float4*>(part);
  float4 v = {0.f, 0.f, 0.f, 0.f};
  for (int c = sub * 32; c < sub * 32 + 32; ++c) {
    const float4 p = p4[(size_t)c * 8192 + g];
    v.x += p.x; v.y += p.y; v.z += p.z; v.w += p.w;
  }
#pragma unroll
  for (int off = 1; off < 4; off <<= 1) {
    v.x += __shfl_xor(v.x, off, 64);
    v.y += __shfl_xor(v.y, off, 64);
    v.z += __shfl_xor(v.z, off, 64);
    v.w += __shfl_xor(v.w, off, 64);
  }
  if (sub == 0) {
    const float4 hv = reinterpret_cast<const float4*>(base)[g];
    const float4 o = {v.x + hv.x, v.y + hv.y, v.z + hv.z, v.w + hv.w};
    reinterpret_cast<float4*>(out)[g] = o;
  }
}

// ---------- fc1 with fused LN2: 512 blocks = 32 jt x 16 ck (2/CU)
__global__ __launch_bounds__(256) void fc1_ln(
    const float* __restrict__ hidden2, const float* __restrict__ w,
    const float* __restrict__ bias, const float* __restrict__ W,
    float* __restrict__ part) {
  __shared__ float mu[8], rsd[8];
  __shared__ float xs[256 * 8];
  const int t = threadIdx.x;
  const int jt = blockIdx.x & 31, ck = blockIdx.x >> 5;
  const size_t i0 = (size_t)ck * 256;
  ln_stats256(hidden2, t, mu, rsd);
  __syncthreads();
#pragma unroll
  for (int r = 0; r < 8; ++r) {
    const int idx = r * 256 + t;
    const int i = idx >> 3, b = idx & 7;
    const int ii = (int)i0 + i;
    const float v = hidden2[(size_t)b * HIDDIM + ii];
    xs[idx] = (v - mu[b]) * rsd[b] * (w[ii] + 1.f) + bias[ii];
  }
  __syncthreads();
  gemm_core(W, 2 * FFNDIM, i0, 256, jt * 1024, xs,
            part + (size_t)ck * 8 * (2 * FFNDIM), t);
}

// ---------- fc2 with fused silu-gate: 512 blocks = 4 jt x 128 ck (2/CU)
__global__ __launch_bounds__(256) void fc2_gate(
    const float* __restrict__ part1, const float* __restrict__ W,
    float* __restrict__ part) {
  __shared__ float xs[128 * 8];
  const int t = threadIdx.x;
  const int jt = blockIdx.x & 3, ck = blockIdx.x >> 2;
  const size_t i0 = (size_t)ck * 128;
  const int b = t >> 5, lane = t & 31;
#pragma unroll
  for (int p = 0; p < 4; ++p) {
    const int jl = p * 32 + lane;
    float h1 = 0.f, h2 = 0.f;
    for (int c = 0; c < 16; ++c) {
      const float* pp = part1 + ((size_t)(c * 8 + b)) * (2 * FFNDIM) + i0 + jl;
      h1 += pp[0];
      h2 += pp[FFNDIM];
    }
    xs[jl * 8 + b] = (h1 / (1.f + __expf(-h1))) * h2;
  }
  __syncthreads();
  gemm_core(W, HIDDIM, i0, 128, jt * 1024, xs, part + (size_t)ck * 8 * HIDDIM, t);
}

extern "C" void kernel_launch(void* const* d_in, const int* in_sizes, int n_in,
                              void* d_out, int out_size, void* d_ws, size_t ws_size,
                              hipStream_t stream) {
  const float* hs = (const float*)d_in[0];
  const float* kc = (const float*)d_in[1];
  const float* vc = (const float*)d_in[2];
  const float* wqkv = (const float*)d_in[3];
  const float* wdense = (const float*)d_in[4];
  const float* wfc1 = (const float*)d_in[5];
  const float* wfc2 = (const float*)d_in[6];
  const float* ln1w = (const float*)d_in[7];
  const float* ln1b = (const float*)d_in[8];
  const float* ln2w = (const float*)d_in[9];
  const float* ln2b = (const float*)d_in[10];
  const int* posp = (const int*)d_in[11];
  float* out = (float*)d_out;

  float* ws = (float*)d_ws;
  float* qws = ws;                  // 32768
  float* kws = qws + 32768;         // 32768
  float* vws = kws + 32768;         // 32768
  float* hidden2 = vws + 32768;     // 32768
  float* Mp = hidden2 + 32768;      // 4096
  float* Lp = Mp + 4096;            // 4096
  float* Ap = Lp + 4096;            // 524288
  float* part1 = Ap + 524288;       // 6.3M (qkv: 64 ck; then fc1: 16 ck)
  float* part2 = part1 + 6291456;   // 4.2M (dense: 128 ck; then fc2: 128 ck)

  // 1. qkv = LN1(hs) @ w_qkv   (768 blocks, 3/CU)
  qkv_ln<<<768, 256, 0, stream>>>(hs, ln1w, ln1b, wqkv, part1);
  // 2. reduce 64 chunks + rope
  rope_reduce<<<256, 128, 0, stream>>>(part1, 64, posp, qws, kws, vws);
  // 3. attention split over 16 s-chunks
  attn_split<<<dim3(16, NHEAD, NB), 256, 0, stream>>>(kc, vc, qws, kws, vws, posp, Mp, Lp, Ap);
  // 4. dense = combine(attn) @ w_dense  (512 blocks, 2/CU)
  dense_comb<<<512, 256, 0, stream>>>(Mp, Lp, Ap, posp, wdense, part2);
  // 5. hidden2 = hs + sum(128 partials)
  reduce_add4<<<128, 256, 0, stream>>>(part2, hs, hidden2);
  // 6. h = LN2(hidden2) @ w_fc1  (512 blocks, 2/CU)
  fc1_ln<<<512, 256, 0, stream>>>(hidden2, ln2w, ln2b, wfc1, part1);
  // 7. y = silu-gate(fc1 partials) @ w_fc2  (512 blocks, 2/CU)
  fc2_gate<<<512, 256, 0, stream>>>(part1, wfc2, part2);
  // 8. out = hidden2 + sum(128 partials)
  reduce_add4<<<128, 256, 0, stream>>>(part2, hidden2, out);
}